// Round 7
// baseline (696.175 us; speedup 1.0000x reference)
//
#include <hip/hip_runtime.h>

typedef _Float16 f16;
typedef __attribute__((ext_vector_type(8))) _Float16 half8;   // 16x16x32 A/B frag
typedef __attribute__((ext_vector_type(4))) _Float16 half4;   // 16x16x16 A/B frag
typedef __attribute__((ext_vector_type(4))) float   f4;       // MFMA C/D

#define NTOK   196
#define MROWS  50176            // 256 * 196
#define HIDN   1536
#define HPC    192              // per-head channels in h (q32|k32|v128)
#define DHD    1024             // H * 128
#define EPSV   1e-5f
#define SCALEV 0.17677669529663687f

// async global->LDS, 16B per lane; LDS dest is wave-uniform base + lane*16
#define GLD16(gp, lp) __builtin_amdgcn_global_load_lds( \
    (const __attribute__((address_space(1))) unsigned int*)(gp), \
    (__attribute__((address_space(3))) unsigned int*)(lp), 16, 0, 0)

// rotation swizzle: spreads banks for reads (row bits 0-3) AND writes (row bits 3-5)
__device__ inline int swz8(int row) { return (((row & 7) ^ ((row >> 3) & 7))) * 8; }

// ---------------- f32 -> f16 convert (vectorized) — weights only now
__global__ void cvt_f32_f16(const float* __restrict__ src, f16* __restrict__ dst, int n4)
{
    int i = blockIdx.x * blockDim.x + threadIdx.x;
    if (i < n4) {
        float4 v = *(const float4*)&src[i * 4];
        half4 h = { (f16)v.x, (f16)v.y, (f16)v.z, (f16)v.w };
        *(half4*)&dst[i * 4] = h;
    }
}

// ---------------- bias_full[h][208 q][224 k] f16; pad (q>=196 or k>=196) = -30000
__global__ void build_bias(const float* __restrict__ bt, const int* __restrict__ idxs,
                           f16* __restrict__ bf)
{
    int i = blockIdx.x * 256 + threadIdx.x;
    if (i >= 8 * 208 * 224) return;
    int k = i % 224, q = (i / 224) % 208, h = i / (224 * 208);
    float v = -30000.f;
    if (q < NTOK && k < NTOK) v = bt[h * NTOK + idxs[q * NTOK + k]];
    bf[i] = (f16)v;
}

// ---------------- GEMM1: h = x @ Wqkv^T  (A f32 with fused cvt, B f16; f16 out + BN stats)
__global__ __launch_bounds__(256) void gemm1_qkv(
    const float* __restrict__ A, const f16* __restrict__ B,
    f16* __restrict__ C, float* __restrict__ gsum, float* __restrict__ gsq)
{
    const int K = 256, ldc = HIDN;
    __shared__ f16 As[128 * 40];      // padded (manual staging with cvt)
    __shared__ f16 Bs[128 * 32];      // unpadded (global_load_lds)
    __shared__ float ssum[128], ssq[128];

    const int t = threadIdx.x;
    const int m0 = blockIdx.x * 128, n0 = blockIdx.y * 128;
    const int wid = t >> 6, lane = t & 63, quad = lane >> 4, lm = lane & 15;
    const int wm = (wid >> 1) * 64, wn = (wid & 1) * 64;

    // A staging: thread covers 16 f32 of one row-half
    const int ar = t >> 1, ah = (t & 1) * 16;
    const float* Arow = A + (long)(m0 + ar) * K + ah;

    // B staging via GLD16
    const int lr = lane >> 2, lc = (lane & 3) * 8;
    f16* Bs0 = &Bs[(wid * 2 + 0) * 512];
    f16* Bs1 = &Bs[(wid * 2 + 1) * 512];
    const f16* Bb = B + (long)(n0 + wid * 32 + lr) * K + lc;

    f4 acc[4][4] = {};

    for (int k0 = 0; k0 < K; k0 += 32) {
        float4 v0 = *(const float4*)&Arow[k0];
        float4 v1 = *(const float4*)&Arow[k0 + 4];
        float4 v2 = *(const float4*)&Arow[k0 + 8];
        float4 v3 = *(const float4*)&Arow[k0 + 12];
        GLD16(Bb + k0,          Bs0);
        GLD16(Bb + 16 * K + k0, Bs1);
        half8 h0 = { (f16)v0.x, (f16)v0.y, (f16)v0.z, (f16)v0.w,
                     (f16)v1.x, (f16)v1.y, (f16)v1.z, (f16)v1.w };
        half8 h1 = { (f16)v2.x, (f16)v2.y, (f16)v2.z, (f16)v2.w,
                     (f16)v3.x, (f16)v3.y, (f16)v3.z, (f16)v3.w };
        *(half8*)&As[ar * 40 + ah]     = h0;
        *(half8*)&As[ar * 40 + ah + 8] = h1;
        __syncthreads();
        half8 a[4], b[4];
        #pragma unroll
        for (int i = 0; i < 4; ++i) a[i] = *(const half8*)&As[(wm + i*16 + lm) * 40 + quad * 8];
        #pragma unroll
        for (int j = 0; j < 4; ++j) b[j] = *(const half8*)&Bs[(wn + j*16 + lm) * 32 + quad * 8];
        #pragma unroll
        for (int i = 0; i < 4; ++i)
            #pragma unroll
            for (int j = 0; j < 4; ++j)
                acc[i][j] = __builtin_amdgcn_mfma_f32_16x16x32_f16(a[i], b[j], acc[i][j], 0, 0, 0);
        __syncthreads();
    }

    if (t < 128) { ssum[t] = 0.f; ssq[t] = 0.f; }
    __syncthreads();

    #pragma unroll
    for (int j = 0; j < 4; ++j) {
        int nl = wn + j*16 + lm;
        float psum = 0.f, psq = 0.f;
        #pragma unroll
        for (int i = 0; i < 4; ++i) {
            #pragma unroll
            for (int r = 0; r < 4; ++r) {
                int ml = wm + i*16 + quad*4 + r;
                float v = acc[i][j][r];
                f16 uh = (f16)v;
                float vb = (float)uh;
                C[(long)(m0 + ml) * ldc + n0 + nl] = uh;
                psum += vb; psq += vb * vb;
            }
        }
        atomicAdd(&ssum[nl], psum);
        atomicAdd(&ssq[nl], psq);
    }
    __syncthreads();
    if (t < 128) {
        atomicAdd(&gsum[n0 + t], ssum[t]);
        atomicAdd(&gsq[n0 + t],  ssq[t]);
    }
}

// ---------------- GEMM2: p = o @ Wproj^T  (f16 in, f16 out + BN stats)
__global__ __launch_bounds__(256) void gemm2_proj(
    const f16* __restrict__ A, const f16* __restrict__ B,
    f16* __restrict__ C, float* __restrict__ gsum, float* __restrict__ gsq)
{
    const int K = 1024, ldc = 256;
    __shared__ f16 As[128 * 32];
    __shared__ f16 Bs[128 * 32];
    __shared__ float ssum[128], ssq[128];

    const int t = threadIdx.x;
    const int m0 = blockIdx.x * 128, n0 = blockIdx.y * 128;
    const int wid = t >> 6, lane = t & 63, quad = lane >> 4, lm = lane & 15;
    const int wm = (wid >> 1) * 64, wn = (wid & 1) * 64;

    const int lr = lane >> 2, lc = (lane & 3) * 8;
    f16* As0 = &As[(wid * 2 + 0) * 512];
    f16* As1 = &As[(wid * 2 + 1) * 512];
    f16* Bs0 = &Bs[(wid * 2 + 0) * 512];
    f16* Bs1 = &Bs[(wid * 2 + 1) * 512];
    const f16* Ab = A + (long)(m0 + wid * 32 + lr) * K + lc;
    const f16* Bb = B + (long)(n0 + wid * 32 + lr) * K + lc;

    f4 acc[4][4] = {};

    for (int k0 = 0; k0 < K; k0 += 32) {
        GLD16(Ab + k0,          As0);
        GLD16(Ab + 16 * K + k0, As1);
        GLD16(Bb + k0,          Bs0);
        GLD16(Bb + 16 * K + k0, Bs1);
        __syncthreads();
        half8 a[4], b[4];
        #pragma unroll
        for (int i = 0; i < 4; ++i) a[i] = *(const half8*)&As[(wm + i*16 + lm) * 32 + quad * 8];
        #pragma unroll
        for (int j = 0; j < 4; ++j) b[j] = *(const half8*)&Bs[(wn + j*16 + lm) * 32 + quad * 8];
        #pragma unroll
        for (int i = 0; i < 4; ++i)
            #pragma unroll
            for (int j = 0; j < 4; ++j)
                acc[i][j] = __builtin_amdgcn_mfma_f32_16x16x32_f16(a[i], b[j], acc[i][j], 0, 0, 0);
        __syncthreads();
    }

    if (t < 128) { ssum[t] = 0.f; ssq[t] = 0.f; }
    __syncthreads();

    #pragma unroll
    for (int j = 0; j < 4; ++j) {
        int nl = wn + j*16 + lm;
        float psum = 0.f, psq = 0.f;
        #pragma unroll
        for (int i = 0; i < 4; ++i) {
            #pragma unroll
            for (int r = 0; r < 4; ++r) {
                int ml = wm + i*16 + quad*4 + r;
                float v = acc[i][j][r];
                f16 uh = (f16)v;
                float vb = (float)uh;
                C[(long)(m0 + ml) * ldc + n0 + nl] = uh;
                psum += vb; psq += vb * vb;
            }
        }
        atomicAdd(&ssum[nl], psum);
        atomicAdd(&ssq[nl], psq);
    }
    __syncthreads();
    if (t < 128) {
        atomicAdd(&gsum[n0 + t], ssum[t]);
        atomicAdd(&gsq[n0 + t],  ssq[t]);
    }
}

__global__ void bn_fin(const float* __restrict__ gsum, const float* __restrict__ gsq,
                       const float* __restrict__ g, const float* __restrict__ b,
                       float* __restrict__ a_out, float* __restrict__ s_out, int nch)
{
    int c = blockIdx.x * blockDim.x + threadIdx.x;
    if (c >= nch) return;
    float inv  = 1.f / (float)MROWS;
    float mean = gsum[c] * inv;
    float var  = gsq[c] * inv - mean * mean;
    float a    = g[c] * rsqrtf(var + EPSV);
    a_out[c] = a;
    s_out[c] = b[c] - mean * a;
}

// ---------------- apply BN1 affine in-place to q/k columns (0..63 of each head's 192)
__global__ __launch_bounds__(256) void bn1_qk(
    f16* __restrict__ h, const float* __restrict__ a1, const float* __restrict__ s1)
{
    int i = blockIdx.x * 256 + threadIdx.x;      // 50176 rows * 64 half8-chunks
    int row = i >> 6, j = i & 63;
    int hh = j >> 3, c8 = (j & 7) * 8;
    size_t off = (size_t)row * HIDN + hh * HPC + c8;
    int ci = hh * HPC + c8;
    half8 v = *(half8*)(h + off);
    float4 a0 = *(const float4*)&a1[ci], a4 = *(const float4*)&a1[ci + 4];
    float4 s0 = *(const float4*)&s1[ci], s4 = *(const float4*)&s1[ci + 4];
    half8 o;
    o[0] = (f16)((float)v[0] * a0.x + s0.x);
    o[1] = (f16)((float)v[1] * a0.y + s0.y);
    o[2] = (f16)((float)v[2] * a0.z + s0.z);
    o[3] = (f16)((float)v[3] * a0.w + s0.w);
    o[4] = (f16)((float)v[4] * a4.x + s4.x);
    o[5] = (f16)((float)v[5] * a4.y + s4.y);
    o[6] = (f16)((float)v[6] * a4.z + s4.z);
    o[7] = (f16)((float)v[7] * a4.w + s4.w);
    *(half8*)(h + off) = o;
}

// ---------------- attention: one block (8 waves) per (batch, head), 2 blocks/CU.
// S^T trick keeps P in registers; V in swizzled LDS; o staged through wave-private
// LDS so obuf stores are 256B-contiguous rows (dwordx4) — no write amplification.
__global__ __launch_bounds__(512, 4) void attn_kernel(
    const f16* __restrict__ hbuf, const float* __restrict__ a1, const float* __restrict__ s1,
    const f16* __restrict__ bf, f16* __restrict__ obuf)
{
    __shared__ f16   vT[128][208];     // 53,248 B; phys col = (kc + swz8(c)) mod 208
    __shared__ f16   ost[8][8][140];   // 17,920 B; per-wave o staging (8 rows x 128 ch)
    __shared__ float af[128], sf[128]; // v-channel affine

    const int t  = threadIdx.x;
    const int bb = blockIdx.x >> 3;
    const int hh = blockIdx.x & 7;
    const int wid = t >> 6, lane = t & 63, quad = lane >> 4, lm = lane & 15;

    if (t < 128) { af[t] = a1[hh * HPC + 64 + t]; sf[t] = s1[hh * HPC + 64 + t]; }
    // zero pad cols kc = 196..207
    for (int i = t; i < 1536; i += 512) {
        int c = i & 127, kc = 196 + (i >> 7);
        int p = kc + swz8(c); if (p >= 208) p -= 208;
        vT[c][p] = (f16)0.f;
    }
    __syncthreads();

    // stage V with affine (transposed, swizzled)
    {
        int tc = t & 15;
        for (int rr = t >> 4; rr < NTOK; rr += 32) {
            const f16* hrow = hbuf + (size_t)(bb * NTOK + rr) * HIDN + hh * HPC + 64;
            half8 raw = *(const half8*)(hrow + tc * 8);
            #pragma unroll
            for (int e = 0; e < 8; ++e) {
                int c = tc * 8 + e;
                int p = rr + swz8(c); if (p >= 208) p -= 208;
                vT[c][p] = (f16)((float)raw[e] * af[c] + sf[c]);
            }
        }
    }
    __syncthreads();

    const f16* kb  = hbuf + (size_t)(bb * NTOK) * HIDN + hh * HPC + 32;
    const f16* qb  = hbuf + (size_t)(bb * NTOK) * HIDN + hh * HPC;
    const f16* bfh = bf + hh * 208 * 224;

    const int mt0 = wid, mt1 = wid + 8;
    const int nmt = (mt1 < 13) ? 2 : 1;

    half8 bq0 = *(const half8*)(qb + (size_t)(mt0 * 16 + lm) * HIDN + quad * 8);
    half8 bq1 = bq0;
    if (nmt == 2) bq1 = *(const half8*)(qb + (size_t)(mt1 * 16 + lm) * HIDN + quad * 8);

    // S^T: D[kc][q], kc = nt*16 + quad*4 + r, q = lm  (each ak feeds both q-tiles)
    f4 sA[13], sB[13];
    #pragma unroll
    for (int nt = 0; nt < 13; ++nt) {
        half8 ak = *(const half8*)(kb + (size_t)(nt * 16 + lm) * HIDN + quad * 8);
        f4 z = {};
        sA[nt] = __builtin_amdgcn_mfma_f32_16x16x32_f16(ak, bq0, z, 0, 0, 0);
        if (nmt == 2) sB[nt] = __builtin_amdgcn_mfma_f32_16x16x32_f16(ak, bq1, z, 0, 0, 0);
    }

    half4 ap[2][13];
    {   // pass 0 softmax
        #pragma unroll
        for (int nt = 0; nt < 13; ++nt) {
            half4 bv = *(const half4*)(bfh + (mt0 * 16 + lm) * 224 + nt * 16 + quad * 4);
            #pragma unroll
            for (int r = 0; r < 4; ++r) sA[nt][r] = sA[nt][r] * SCALEV + (float)bv[r];
        }
        float mx = sA[0][0];
        #pragma unroll
        for (int nt = 0; nt < 13; ++nt)
            #pragma unroll
            for (int r = 0; r < 4; ++r) mx = fmaxf(mx, sA[nt][r]);
        mx = fmaxf(mx, __shfl_xor(mx, 16));
        mx = fmaxf(mx, __shfl_xor(mx, 32));
        float sum = 0.f;
        #pragma unroll
        for (int nt = 0; nt < 13; ++nt)
            #pragma unroll
            for (int r = 0; r < 4; ++r) { float e = __expf(sA[nt][r] - mx); sA[nt][r] = e; sum += e; }
        sum += __shfl_xor(sum, 16);
        sum += __shfl_xor(sum, 32);
        float ri = 1.f / sum;
        #pragma unroll
        for (int nt = 0; nt < 13; ++nt) {
            half4 p = { (f16)(sA[nt][0] * ri), (f16)(sA[nt][1] * ri),
                        (f16)(sA[nt][2] * ri), (f16)(sA[nt][3] * ri) };
            ap[0][nt] = p;
        }
    }
    if (nmt == 2) {   // pass 1 softmax
        #pragma unroll
        for (int nt = 0; nt < 13; ++nt) {
            half4 bv = *(const half4*)(bfh + (mt1 * 16 + lm) * 224 + nt * 16 + quad * 4);
            #pragma unroll
            for (int r = 0; r < 4; ++r) sB[nt][r] = sB[nt][r] * SCALEV + (float)bv[r];
        }
        float mx = sB[0][0];
        #pragma unroll
        for (int nt = 0; nt < 13; ++nt)
            #pragma unroll
            for (int r = 0; r < 4; ++r) mx = fmaxf(mx, sB[nt][r]);
        mx = fmaxf(mx, __shfl_xor(mx, 16));
        mx = fmaxf(mx, __shfl_xor(mx, 32));
        float sum = 0.f;
        #pragma unroll
        for (int nt = 0; nt < 13; ++nt)
            #pragma unroll
            for (int r = 0; r < 4; ++r) { float e = __expf(sB[nt][r] - mx); sB[nt][r] = e; sum += e; }
        sum += __shfl_xor(sum, 16);
        sum += __shfl_xor(sum, 32);
        float ri = 1.f / sum;
        #pragma unroll
        for (int nt = 0; nt < 13; ++nt) {
            half4 p = { (f16)(sB[nt][0] * ri), (f16)(sB[nt][1] * ri),
                        (f16)(sB[nt][2] * ri), (f16)(sB[nt][3] * ri) };
            ap[1][nt] = p;
        }
    }

    // PV + staged coalesced store, per pass (sequential to cap VGPRs)
    f16 (*myost)[140] = ost[wid];
    for (int pass = 0; pass < nmt; ++pass) {
        const int mt = wid + pass * 8;
        half4 oc[8];
        #pragma unroll
        for (int ct = 0; ct < 8; ++ct) {
            int c = ct * 16 + lm;
            int sc = swz8(c);
            f4 o0 = {};
            #pragma unroll
            for (int kt = 0; kt < 13; ++kt) {
                int p = kt * 16 + quad * 4 + sc; if (p >= 208) p -= 208;
                half4 bv = *(const half4*)&vT[c][p];
                o0 = __builtin_amdgcn_mfma_f32_16x16x16f16(ap[pass][kt], bv, o0, 0, 0, 0);
            }
            #pragma unroll
            for (int r = 0; r < 4; ++r) {
                float v = o0[r];
                oc[ct][r] = (f16)(v * fminf(fmaxf(v + 3.f, 0.f), 6.f) * (1.f / 6.f));
            }
        }
        // stage 8 rows at a time through wave-private LDS, store 256B rows
        #pragma unroll
        for (int rp = 0; rp < 2; ++rp) {
            #pragma unroll
            for (int ct = 0; ct < 8; ++ct)
                #pragma unroll
                for (int rr = 0; rr < 2; ++rr)
                    myost[quad * 2 + rr][ct * 16 + lm] = oc[ct][rp * 2 + rr];
            #pragma unroll
            for (int i2 = 0; i2 < 2; ++i2) {
                int s = i2 * 4 + quad;
                half8 vv = *(const half8*)&myost[s][lm * 8];
                int q = mt * 16 + (s >> 1) * 4 + rp * 2 + (s & 1);
                if (q < NTOK)
                    *(half8*)&obuf[(size_t)(bb * NTOK + q) * DHD + hh * 128 + lm * 8] = vv;
            }
        }
    }
}

__global__ __launch_bounds__(256) void bn_apply(
    const f16* __restrict__ p, float* __restrict__ out,
    const float* __restrict__ a2, const float* __restrict__ s2)
{
    __shared__ float aL[256], sL[256];
    int t = threadIdx.x;
    aL[t] = a2[t]; sL[t] = s2[t];
    __syncthreads();
    long total = (long)MROWS * 256 / 8;
    for (long i = (long)blockIdx.x * 256 + t; i < total; i += (long)gridDim.x * 256) {
        half8 v = *(const half8*)&p[i * 8];
        int cb = (int)((i * 8) & 255);
        float4 o0, o1;
        o0.x = (float)v[0] * aL[cb + 0] + sL[cb + 0];
        o0.y = (float)v[1] * aL[cb + 1] + sL[cb + 1];
        o0.z = (float)v[2] * aL[cb + 2] + sL[cb + 2];
        o0.w = (float)v[3] * aL[cb + 3] + sL[cb + 3];
        o1.x = (float)v[4] * aL[cb + 4] + sL[cb + 4];
        o1.y = (float)v[5] * aL[cb + 5] + sL[cb + 5];
        o1.z = (float)v[6] * aL[cb + 6] + sL[cb + 6];
        o1.w = (float)v[7] * aL[cb + 7] + sL[cb + 7];
        *(float4*)&out[i * 8]     = o0;
        *(float4*)&out[i * 8 + 4] = o1;
    }
}

extern "C" void kernel_launch(void* const* d_in, const int* in_sizes, int n_in,
                              void* d_out, int out_size, void* d_ws, size_t ws_size,
                              hipStream_t stream)
{
    (void)in_sizes; (void)n_in; (void)out_size; (void)ws_size;
    const float* x          = (const float*)d_in[0];
    const float* Wqkv       = (const float*)d_in[1];
    const float* g1         = (const float*)d_in[2];
    const float* b1         = (const float*)d_in[3];
    const float* bias_table = (const float*)d_in[4];
    const float* Wproj      = (const float*)d_in[5];
    const float* g2         = (const float*)d_in[6];
    const float* b2         = (const float*)d_in[7];
    const int*   idxs       = (const int*)d_in[8];
    float*       out        = (float*)d_out;

    char* ws = (char*)d_ws;
    f16* hbuf = (f16*)ws;                                 // [0, 154,140,672)
    f16* obuf = (f16*)(ws + 154140672LL);                 // [154,140,672, 256,901,120)
    f16* wqh  = (f16*)(ws + 154140672LL + 25690112LL);    // overlay obuf (dead before attn)
    f16* wph  = (f16*)ws;                                 // overlay hbuf (dead after attn)
    f16* pbuf = (f16*)(ws + 1048576LL);                   // overlay hbuf (dead after attn), 25.7 MB
    float* stats = (float*)(ws + 256901120LL);
    float* gsum1 = stats;            float* gsq1 = stats + 1536;
    float* gsum2 = stats + 3072;     float* gsq2 = stats + 3328;
    float* a1 = stats + 3584;        float* s1 = a1 + 1536;
    float* a2 = s1 + 1536;           float* s2 = a2 + 256;
    f16* bias_full = (f16*)(ws + 256901120LL + 65536LL);  // 745,472 B

    hipMemsetAsync(stats, 0, 3584 * sizeof(float), stream);

    cvt_f32_f16<<<384, 256, 0, stream>>>(Wqkv, wqh, 98304);
    build_bias<<<1456, 256, 0, stream>>>(bias_table, idxs, bias_full);

    gemm1_qkv<<<dim3(392, 12), 256, 0, stream>>>(x, wqh, hbuf, gsum1, gsq1);
    bn_fin<<<6, 256, 0, stream>>>(gsum1, gsq1, g1, b1, a1, s1, 1536);
    bn1_qk<<<12544, 256, 0, stream>>>(hbuf, a1, s1);

    attn_kernel<<<2048, 512, 0, stream>>>(hbuf, a1, s1, bias_full, obuf);

    cvt_f32_f16<<<256, 256, 0, stream>>>(Wproj, wph, 65536);

    gemm2_proj<<<dim3(392, 2), 256, 0, stream>>>(obuf, wph, pbuf, gsum2, gsq2);
    bn_fin<<<1, 256, 0, stream>>>(gsum2, gsq2, g2, b2, a2, s2, 256);

    bn_apply<<<1024, 256, 0, stream>>>(pbuf, out, a2, s2);
}

// Round 8
// 493.616 us; speedup vs baseline: 1.4104x; 1.4104x over previous
//
#include <hip/hip_runtime.h>

typedef _Float16 f16;
typedef __attribute__((ext_vector_type(8))) _Float16 half8;   // 16x16x32 A/B frag
typedef __attribute__((ext_vector_type(4))) _Float16 half4;   // 16x16x16 A/B frag
typedef __attribute__((ext_vector_type(4))) float   f4;       // MFMA C/D

#define NTOK   196
#define MROWS  50176            // 256 * 196
#define HIDN   1536
#define HPC    192              // per-head channels in h (q32|k32|v128)
#define DHD    1024             // H * 128
#define EPSV   1e-5f
#define SCALEV 0.17677669529663687f

// async global->LDS, 16B per lane; LDS dest is wave-uniform base + lane*16
#define GLD16(gp, lp) __builtin_amdgcn_global_load_lds( \
    (const __attribute__((address_space(1))) unsigned int*)(gp), \
    (__attribute__((address_space(3))) unsigned int*)(lp), 16, 0, 0)

// rotation swizzle: spreads banks for reads (row bits 0-3) AND writes (row bits 3-5)
__device__ inline int swz8(int row) { return (((row & 7) ^ ((row >> 3) & 7))) * 8; }

// ---------------- f32 -> f16 convert (vectorized) — weights only
__global__ void cvt_f32_f16(const float* __restrict__ src, f16* __restrict__ dst, int n4)
{
    int i = blockIdx.x * blockDim.x + threadIdx.x;
    if (i < n4) {
        float4 v = *(const float4*)&src[i * 4];
        half4 h = { (f16)v.x, (f16)v.y, (f16)v.z, (f16)v.w };
        *(half4*)&dst[i * 4] = h;
    }
}

// ---------------- bias_full[h][208 q][224 k] f16; pad (q>=196 or k>=196) = -30000
__global__ void build_bias(const float* __restrict__ bt, const int* __restrict__ idxs,
                           f16* __restrict__ bf)
{
    int i = blockIdx.x * 256 + threadIdx.x;
    if (i >= 8 * 208 * 224) return;
    int k = i % 224, q = (i / 224) % 208, h = i / (224 * 208);
    float v = -30000.f;
    if (q < NTOK && k < NTOK) v = bt[h * NTOK + idxs[q * NTOK + k]];
    bf[i] = (f16)v;
}

// ---------------- GEMM1: h = x @ Wqkv^T  (A f32 with fused cvt, B f16; f16 out + BN stats)
__global__ __launch_bounds__(256) void gemm1_qkv(
    const float* __restrict__ A, const f16* __restrict__ B,
    f16* __restrict__ C, float* __restrict__ gsum, float* __restrict__ gsq)
{
    const int K = 256, ldc = HIDN;
    __shared__ f16 As[128 * 40];      // padded (manual staging with cvt)
    __shared__ f16 Bs[128 * 32];      // unpadded (global_load_lds)
    __shared__ float ssum[128], ssq[128];

    const int t = threadIdx.x;
    const int m0 = blockIdx.x * 128, n0 = blockIdx.y * 128;
    const int wid = t >> 6, lane = t & 63, quad = lane >> 4, lm = lane & 15;
    const int wm = (wid >> 1) * 64, wn = (wid & 1) * 64;

    const int ar = t >> 1, ah = (t & 1) * 16;
    const float* Arow = A + (long)(m0 + ar) * K + ah;

    const int lr = lane >> 2, lc = (lane & 3) * 8;
    f16* Bs0 = &Bs[(wid * 2 + 0) * 512];
    f16* Bs1 = &Bs[(wid * 2 + 1) * 512];
    const f16* Bb = B + (long)(n0 + wid * 32 + lr) * K + lc;

    f4 acc[4][4] = {};

    for (int k0 = 0; k0 < K; k0 += 32) {
        float4 v0 = *(const float4*)&Arow[k0];
        float4 v1 = *(const float4*)&Arow[k0 + 4];
        float4 v2 = *(const float4*)&Arow[k0 + 8];
        float4 v3 = *(const float4*)&Arow[k0 + 12];
        GLD16(Bb + k0,          Bs0);
        GLD16(Bb + 16 * K + k0, Bs1);
        half8 h0 = { (f16)v0.x, (f16)v0.y, (f16)v0.z, (f16)v0.w,
                     (f16)v1.x, (f16)v1.y, (f16)v1.z, (f16)v1.w };
        half8 h1 = { (f16)v2.x, (f16)v2.y, (f16)v2.z, (f16)v2.w,
                     (f16)v3.x, (f16)v3.y, (f16)v3.z, (f16)v3.w };
        *(half8*)&As[ar * 40 + ah]     = h0;
        *(half8*)&As[ar * 40 + ah + 8] = h1;
        __syncthreads();
        half8 a[4], b[4];
        #pragma unroll
        for (int i = 0; i < 4; ++i) a[i] = *(const half8*)&As[(wm + i*16 + lm) * 40 + quad * 8];
        #pragma unroll
        for (int j = 0; j < 4; ++j) b[j] = *(const half8*)&Bs[(wn + j*16 + lm) * 32 + quad * 8];
        #pragma unroll
        for (int i = 0; i < 4; ++i)
            #pragma unroll
            for (int j = 0; j < 4; ++j)
                acc[i][j] = __builtin_amdgcn_mfma_f32_16x16x32_f16(a[i], b[j], acc[i][j], 0, 0, 0);
        __syncthreads();
    }

    if (t < 128) { ssum[t] = 0.f; ssq[t] = 0.f; }
    __syncthreads();

    #pragma unroll
    for (int j = 0; j < 4; ++j) {
        int nl = wn + j*16 + lm;
        float psum = 0.f, psq = 0.f;
        #pragma unroll
        for (int i = 0; i < 4; ++i) {
            #pragma unroll
            for (int r = 0; r < 4; ++r) {
                int ml = wm + i*16 + quad*4 + r;
                float v = acc[i][j][r];
                f16 uh = (f16)v;
                float vb = (float)uh;
                C[(long)(m0 + ml) * ldc + n0 + nl] = uh;
                psum += vb; psq += vb * vb;
            }
        }
        atomicAdd(&ssum[nl], psum);
        atomicAdd(&ssq[nl], psq);
    }
    __syncthreads();
    if (t < 128) {
        atomicAdd(&gsum[n0 + t], ssum[t]);
        atomicAdd(&gsq[n0 + t],  ssq[t]);
    }
}

// ---------------- GEMM2: p = o @ Wproj^T  (f16 in, f16 out + BN stats)
__global__ __launch_bounds__(256) void gemm2_proj(
    const f16* __restrict__ A, const f16* __restrict__ B,
    f16* __restrict__ C, float* __restrict__ gsum, float* __restrict__ gsq)
{
    const int K = 1024, ldc = 256;
    __shared__ f16 As[128 * 32];
    __shared__ f16 Bs[128 * 32];
    __shared__ float ssum[128], ssq[128];

    const int t = threadIdx.x;
    const int m0 = blockIdx.x * 128, n0 = blockIdx.y * 128;
    const int wid = t >> 6, lane = t & 63, quad = lane >> 4, lm = lane & 15;
    const int wm = (wid >> 1) * 64, wn = (wid & 1) * 64;

    const int lr = lane >> 2, lc = (lane & 3) * 8;
    f16* As0 = &As[(wid * 2 + 0) * 512];
    f16* As1 = &As[(wid * 2 + 1) * 512];
    f16* Bs0 = &Bs[(wid * 2 + 0) * 512];
    f16* Bs1 = &Bs[(wid * 2 + 1) * 512];
    const f16* Ab = A + (long)(m0 + wid * 32 + lr) * K + lc;
    const f16* Bb = B + (long)(n0 + wid * 32 + lr) * K + lc;

    f4 acc[4][4] = {};

    for (int k0 = 0; k0 < K; k0 += 32) {
        GLD16(Ab + k0,          As0);
        GLD16(Ab + 16 * K + k0, As1);
        GLD16(Bb + k0,          Bs0);
        GLD16(Bb + 16 * K + k0, Bs1);
        __syncthreads();
        half8 a[4], b[4];
        #pragma unroll
        for (int i = 0; i < 4; ++i) a[i] = *(const half8*)&As[(wm + i*16 + lm) * 32 + quad * 8];
        #pragma unroll
        for (int j = 0; j < 4; ++j) b[j] = *(const half8*)&Bs[(wn + j*16 + lm) * 32 + quad * 8];
        #pragma unroll
        for (int i = 0; i < 4; ++i)
            #pragma unroll
            for (int j = 0; j < 4; ++j)
                acc[i][j] = __builtin_amdgcn_mfma_f32_16x16x32_f16(a[i], b[j], acc[i][j], 0, 0, 0);
        __syncthreads();
    }

    if (t < 128) { ssum[t] = 0.f; ssq[t] = 0.f; }
    __syncthreads();

    #pragma unroll
    for (int j = 0; j < 4; ++j) {
        int nl = wn + j*16 + lm;
        float psum = 0.f, psq = 0.f;
        #pragma unroll
        for (int i = 0; i < 4; ++i) {
            #pragma unroll
            for (int r = 0; r < 4; ++r) {
                int ml = wm + i*16 + quad*4 + r;
                float v = acc[i][j][r];
                f16 uh = (f16)v;
                float vb = (float)uh;
                C[(long)(m0 + ml) * ldc + n0 + nl] = uh;
                psum += vb; psq += vb * vb;
            }
        }
        atomicAdd(&ssum[nl], psum);
        atomicAdd(&ssq[nl], psq);
    }
    __syncthreads();
    if (t < 128) {
        atomicAdd(&gsum[n0 + t], ssum[t]);
        atomicAdd(&gsq[n0 + t],  ssq[t]);
    }
}

__global__ void bn_fin(const float* __restrict__ gsum, const float* __restrict__ gsq,
                       const float* __restrict__ g, const float* __restrict__ b,
                       float* __restrict__ a_out, float* __restrict__ s_out, int nch)
{
    int c = blockIdx.x * blockDim.x + threadIdx.x;
    if (c >= nch) return;
    float inv  = 1.f / (float)MROWS;
    float mean = gsum[c] * inv;
    float var  = gsq[c] * inv - mean * mean;
    float a    = g[c] * rsqrtf(var + EPSV);
    a_out[c] = a;
    s_out[c] = b[c] - mean * a;
}

// ---------------- apply BN1 affine in-place to q/k columns (0..63 of each head's 192)
__global__ __launch_bounds__(256) void bn1_qk(
    f16* __restrict__ h, const float* __restrict__ a1, const float* __restrict__ s1)
{
    int i = blockIdx.x * 256 + threadIdx.x;      // 50176 rows * 64 half8-chunks
    int row = i >> 6, j = i & 63;
    int hh = j >> 3, c8 = (j & 7) * 8;
    size_t off = (size_t)row * HIDN + hh * HPC + c8;
    int ci = hh * HPC + c8;
    half8 v = *(half8*)(h + off);
    float4 a0 = *(const float4*)&a1[ci], a4 = *(const float4*)&a1[ci + 4];
    float4 s0 = *(const float4*)&s1[ci], s4 = *(const float4*)&s1[ci + 4];
    half8 o;
    o[0] = (f16)((float)v[0] * a0.x + s0.x);
    o[1] = (f16)((float)v[1] * a0.y + s0.y);
    o[2] = (f16)((float)v[2] * a0.z + s0.z);
    o[3] = (f16)((float)v[3] * a0.w + s0.w);
    o[4] = (f16)((float)v[4] * a4.x + s4.x);
    o[5] = (f16)((float)v[5] * a4.y + s4.y);
    o[6] = (f16)((float)v[6] * a4.z + s4.z);
    o[7] = (f16)((float)v[7] * a4.w + s4.w);
    *(half8*)(h + off) = o;
}

// ---------------- attention: one block (8 waves) per (batch, head), 2 blocks/CU.
// S^T trick keeps P in registers; V in swizzled LDS; per-pass lambda with ALL
// constant-index locals (no dynamic array indexing => no scratch spills);
// o staged through wave-private LDS for 256B-contiguous dwordx4 stores.
__global__ __launch_bounds__(512, 4) void attn_kernel(
    const f16* __restrict__ hbuf, const float* __restrict__ a1, const float* __restrict__ s1,
    const f16* __restrict__ bf, f16* __restrict__ obuf)
{
    __shared__ f16   vT[128][208];     // 53,248 B; phys col = (kc + swz8(c)) mod 208
    __shared__ f16   ost[8][8][140];   // 17,920 B; per-wave o staging
    __shared__ float af[128], sf[128]; // v-channel affine

    const int t  = threadIdx.x;
    const int bb = blockIdx.x >> 3;
    const int hh = blockIdx.x & 7;
    const int wid = t >> 6, lane = t & 63, quad = lane >> 4, lm = lane & 15;

    if (t < 128) { af[t] = a1[hh * HPC + 64 + t]; sf[t] = s1[hh * HPC + 64 + t]; }
    // zero pad cols kc = 196..207
    for (int i = t; i < 1536; i += 512) {
        int c = i & 127, kc = 196 + (i >> 7);
        int p = kc + swz8(c); if (p >= 208) p -= 208;
        vT[c][p] = (f16)0.f;
    }
    __syncthreads();

    // stage V with affine (transposed, swizzled)
    {
        int tc = t & 15;
        for (int rr = t >> 4; rr < NTOK; rr += 32) {
            const f16* hrow = hbuf + (size_t)(bb * NTOK + rr) * HIDN + hh * HPC + 64;
            half8 raw = *(const half8*)(hrow + tc * 8);
            #pragma unroll
            for (int e = 0; e < 8; ++e) {
                int c = tc * 8 + e;
                int p = rr + swz8(c); if (p >= 208) p -= 208;
                vT[c][p] = (f16)((float)raw[e] * af[c] + sf[c]);
            }
        }
    }
    __syncthreads();

    const f16* kb  = hbuf + (size_t)(bb * NTOK) * HIDN + hh * HPC + 32;
    const f16* qb  = hbuf + (size_t)(bb * NTOK) * HIDN + hh * HPC;
    const f16* bfh = bf + hh * 208 * 224;
    f16 (*myost)[140] = ost[wid];

    auto do_pass = [&](int mt) {
        // ---- S^T = k q^T: D[kc][q], kc = nt*16+quad*4+r, q = lm
        half8 bq = *(const half8*)(qb + (size_t)(mt * 16 + lm) * HIDN + quad * 8);
        f4 sreg[13];
        #pragma unroll
        for (int nt = 0; nt < 13; ++nt) {
            half8 ak = *(const half8*)(kb + (size_t)(nt * 16 + lm) * HIDN + quad * 8);
            f4 z = {};
            sreg[nt] = __builtin_amdgcn_mfma_f32_16x16x32_f16(ak, bq, z, 0, 0, 0);
        }
        // ---- scale + bias (mask baked into bias pad)
        #pragma unroll
        for (int nt = 0; nt < 13; ++nt) {
            half4 bv = *(const half4*)(bfh + (mt * 16 + lm) * 224 + nt * 16 + quad * 4);
            #pragma unroll
            for (int r = 0; r < 4; ++r) sreg[nt][r] = sreg[nt][r] * SCALEV + (float)bv[r];
        }
        // ---- softmax: in-lane 52 + 2 cross-quad shuffles
        float mx = sreg[0][0];
        #pragma unroll
        for (int nt = 0; nt < 13; ++nt)
            #pragma unroll
            for (int r = 0; r < 4; ++r) mx = fmaxf(mx, sreg[nt][r]);
        mx = fmaxf(mx, __shfl_xor(mx, 16));
        mx = fmaxf(mx, __shfl_xor(mx, 32));
        float sum = 0.f;
        #pragma unroll
        for (int nt = 0; nt < 13; ++nt)
            #pragma unroll
            for (int r = 0; r < 4; ++r) { float e = __expf(sreg[nt][r] - mx); sreg[nt][r] = e; sum += e; }
        sum += __shfl_xor(sum, 16);
        sum += __shfl_xor(sum, 32);
        float ri = 1.f / sum;
        half4 ap[13];
        #pragma unroll
        for (int nt = 0; nt < 13; ++nt) {
            half4 p = { (f16)(sreg[nt][0] * ri), (f16)(sreg[nt][1] * ri),
                        (f16)(sreg[nt][2] * ri), (f16)(sreg[nt][3] * ri) };
            ap[nt] = p;
        }
        // ---- PV (P already in 16x16x16 A-layout), hard-swish
        half4 oc[8];
        #pragma unroll
        for (int ct = 0; ct < 8; ++ct) {
            int c = ct * 16 + lm;
            int sc = swz8(c);
            f4 o0 = {};
            #pragma unroll
            for (int kt = 0; kt < 13; ++kt) {
                int p = kt * 16 + quad * 4 + sc; if (p >= 208) p -= 208;
                half4 bv = *(const half4*)&vT[c][p];
                o0 = __builtin_amdgcn_mfma_f32_16x16x16f16(ap[kt], bv, o0, 0, 0, 0);
            }
            #pragma unroll
            for (int r = 0; r < 4; ++r) {
                float v = o0[r];
                oc[ct][r] = (f16)(v * fminf(fmaxf(v + 3.f, 0.f), 6.f) * (1.f / 6.f));
            }
        }
        // ---- stage through wave-private LDS, store 256B-contiguous rows
        #pragma unroll
        for (int rp = 0; rp < 2; ++rp) {
            #pragma unroll
            for (int ct = 0; ct < 8; ++ct)
                #pragma unroll
                for (int rr = 0; rr < 2; ++rr)
                    myost[quad * 2 + rr][ct * 16 + lm] = oc[ct][rp * 2 + rr];
            #pragma unroll
            for (int i2 = 0; i2 < 2; ++i2) {
                int s = i2 * 4 + quad;
                half8 vv = *(const half8*)&myost[s][lm * 8];
                int q = mt * 16 + (s >> 1) * 4 + rp * 2 + (s & 1);
                if (q < NTOK)
                    *(half8*)&obuf[(size_t)(bb * NTOK + q) * DHD + hh * 128 + lm * 8] = vv;
            }
        }
    };

    do_pass(wid);
    if (wid + 8 < 13) do_pass(wid + 8);
}

__global__ __launch_bounds__(256) void bn_apply(
    const f16* __restrict__ p, float* __restrict__ out,
    const float* __restrict__ a2, const float* __restrict__ s2)
{
    __shared__ float aL[256], sL[256];
    int t = threadIdx.x;
    aL[t] = a2[t]; sL[t] = s2[t];
    __syncthreads();
    long total = (long)MROWS * 256 / 8;
    for (long i = (long)blockIdx.x * 256 + t; i < total; i += (long)gridDim.x * 256) {
        half8 v = *(const half8*)&p[i * 8];
        int cb = (int)((i * 8) & 255);
        float4 o0, o1;
        o0.x = (float)v[0] * aL[cb + 0] + sL[cb + 0];
        o0.y = (float)v[1] * aL[cb + 1] + sL[cb + 1];
        o0.z = (float)v[2] * aL[cb + 2] + sL[cb + 2];
        o0.w = (float)v[3] * aL[cb + 3] + sL[cb + 3];
        o1.x = (float)v[4] * aL[cb + 4] + sL[cb + 4];
        o1.y = (float)v[5] * aL[cb + 5] + sL[cb + 5];
        o1.z = (float)v[6] * aL[cb + 6] + sL[cb + 6];
        o1.w = (float)v[7] * aL[cb + 7] + sL[cb + 7];
        *(float4*)&out[i * 8]     = o0;
        *(float4*)&out[i * 8 + 4] = o1;
    }
}

extern "C" void kernel_launch(void* const* d_in, const int* in_sizes, int n_in,
                              void* d_out, int out_size, void* d_ws, size_t ws_size,
                              hipStream_t stream)
{
    (void)in_sizes; (void)n_in; (void)out_size; (void)ws_size;
    const float* x          = (const float*)d_in[0];
    const float* Wqkv       = (const float*)d_in[1];
    const float* g1         = (const float*)d_in[2];
    const float* b1         = (const float*)d_in[3];
    const float* bias_table = (const float*)d_in[4];
    const float* Wproj      = (const float*)d_in[5];
    const float* g2         = (const float*)d_in[6];
    const float* b2         = (const float*)d_in[7];
    const int*   idxs       = (const int*)d_in[8];
    float*       out        = (float*)d_out;

    char* ws = (char*)d_ws;
    f16* hbuf = (f16*)ws;                                 // [0, 154,140,672)
    f16* obuf = (f16*)(ws + 154140672LL);                 // [154,140,672, 256,901,120)
    f16* wqh  = (f16*)(ws + 154140672LL + 25690112LL);    // overlay obuf (dead before attn)
    f16* wph  = (f16*)ws;                                 // overlay hbuf (dead after attn)
    f16* pbuf = (f16*)(ws + 1048576LL);                   // overlay hbuf (dead after attn)
    float* stats = (float*)(ws + 256901120LL);
    float* gsum1 = stats;            float* gsq1 = stats + 1536;
    float* gsum2 = stats + 3072;     float* gsq2 = stats + 3328;
    float* a1 = stats + 3584;        float* s1 = a1 + 1536;
    float* a2 = s1 + 1536;           float* s2 = a2 + 256;
    f16* bias_full = (f16*)(ws + 256901120LL + 65536LL);  // 745,472 B

    hipMemsetAsync(stats, 0, 3584 * sizeof(float), stream);

    cvt_f32_f16<<<384, 256, 0, stream>>>(Wqkv, wqh, 98304);
    build_bias<<<1456, 256, 0, stream>>>(bias_table, idxs, bias_full);

    gemm1_qkv<<<dim3(392, 12), 256, 0, stream>>>(x, wqh, hbuf, gsum1, gsq1);
    bn_fin<<<6, 256, 0, stream>>>(gsum1, gsq1, g1, b1, a1, s1, 1536);
    bn1_qk<<<12544, 256, 0, stream>>>(hbuf, a1, s1);

    attn_kernel<<<2048, 512, 0, stream>>>(hbuf, a1, s1, bias_full, obuf);

    cvt_f32_f16<<<256, 256, 0, stream>>>(Wproj, wph, 65536);

    gemm2_proj<<<dim3(392, 2), 256, 0, stream>>>(obuf, wph, pbuf, gsum2, gsq2);
    bn_fin<<<1, 256, 0, stream>>>(gsum2, gsq2, g2, b2, a2, s2, 256);

    bn_apply<<<1024, 256, 0, stream>>>(pbuf, out, a2, s2);
}